// Round 1
// baseline (2042.048 us; speedup 1.0000x reference)
//
#include <hip/hip_runtime.h>
#include <hip/hip_bf16.h>
#include <math.h>

// ---------------- helpers ----------------
__device__ __forceinline__ float wave_sum(float v) {
#pragma unroll
  for (int m = 1; m < 64; m <<= 1) v += __shfl_xor(v, m, 64);
  return v;
}

__device__ __forceinline__ float gelu_f(float v) {
  return 0.5f * v * (1.0f + erff(v * 0.7071067811865476f));
}

// ---------------- tiny elementwise ----------------
__global__ void k_aux(const float* __restrict__ score, const float* __restrict__ c,
                      const float* __restrict__ d, float* __restrict__ aux, int n) {
  int i = blockIdx.x * blockDim.x + threadIdx.x;
  if (i < n) {
    float z = c[0] * score[i] - d[0];
    aux[i] = 1.0f / (1.0f + expf(-z));
  }
}

// ---------------- CSR build ----------------
__global__ void k_count(const int* __restrict__ ei, int E,
                        int* __restrict__ deg_dst, int* __restrict__ deg_src) {
  int e = blockIdx.x * blockDim.x + threadIdx.x;
  if (e < E) {
    atomicAdd(&deg_src[ei[e]], 1);
    atomicAdd(&deg_dst[ei[E + e]], 1);
  }
}

__global__ __launch_bounds__(1024) void k_scan(const int* __restrict__ degA, int* __restrict__ offA,
                                               const int* __restrict__ degB, int* __restrict__ offB,
                                               int n) {
  const int* dg = blockIdx.x ? degB : degA;
  int* of = blockIdx.x ? offB : offA;
  __shared__ int part[1024];
  int t = threadIdx.x;
  int chunk = (n + 1023) >> 10;
  int lo = t * chunk, hi = min(lo + chunk, n);
  int s = 0;
  for (int i = lo; i < hi; ++i) s += dg[i];
  part[t] = s;
  __syncthreads();
  for (int d1 = 1; d1 < 1024; d1 <<= 1) {
    int v = (t >= d1) ? part[t - d1] : 0;
    __syncthreads();
    part[t] += v;
    __syncthreads();
  }
  int run = (t == 0) ? 0 : part[t - 1];
  for (int i = lo; i < hi; ++i) { of[i] = run; run += dg[i]; }
  if (t == 1023) of[n] = part[1023];
}

__global__ void k_scatter(const int* __restrict__ ei, int E,
                          const int* __restrict__ offs_d, int* __restrict__ cur_d, int* __restrict__ csr_d,
                          const int* __restrict__ offs_s, int* __restrict__ cur_s, int* __restrict__ csr_s) {
  int e = blockIdx.x * blockDim.x + threadIdx.x;
  if (e < E) {
    int s = ei[e], dd = ei[E + e];
    int p = atomicAdd(&cur_d[dd], 1);
    csr_d[offs_d[dd] + p] = s;
    int q = atomicAdd(&cur_s[s], 1);
    csr_s[offs_s[s] + q] = dd;
  }
}

// ---------------- batchnorm stats ----------------
__global__ void k_bnstats(const float* __restrict__ h, float* __restrict__ stats, int total) {
  int t = threadIdx.x;
  int idx = blockIdx.x * 256 + t;
  int stride = gridDim.x * 256;   // multiple of 128 -> fixed column per thread
  float s = 0.f, ss = 0.f;
  for (int i = idx; i < total; i += stride) { float v = h[i]; s += v; ss += v * v; }
  __shared__ float ls[256], lss[256];
  ls[t] = s; lss[t] = ss;
  __syncthreads();
  if (t < 128) {
    s = ls[t] + ls[t + 128];
    ss = lss[t] + lss[t + 128];
    atomicAdd(&stats[t], s);
    atomicAdd(&stats[128 + t], ss);
  }
}

__global__ void k_bnfinal(const float* __restrict__ stats, const float* __restrict__ gamma,
                          const float* __restrict__ beta, float* __restrict__ ab, float invn) {
  int t = threadIdx.x;  // 128 threads
  float mu = stats[t] * invn;
  float var = stats[128 + t] * invn - mu * mu;
  float rs = rsqrtf(var + 1e-5f);
  float a = gamma[t] * rs;
  ab[t] = a;
  ab[128 + t] = beta[t] - mu * a;
}

// ---------------- generic skinny GEMM ----------------
// Y[r, col0+c] = act( (f(X[r,:]) @ W[:, col0+c]) + bias_out[col0+c] )
// f(x,k) = x*scale_in[k] + shift_in[k] (each optional).
// Optionally writes inv_out[r] = inv_mul[r] / max(||row||, 1e-12) (pre-bias/act).
// Two-part input: k < k1 -> X0, else X1 (row length xstride each).
// In-place (Y == X0) is safe: rows are block-exclusive and fully staged
// across all K-chunks before the epilogue writes.
template<int K>
__global__ __launch_bounds__(256) void k_gemm(
    const float* X0, const float* X1, int k1, int xstride,
    const float* __restrict__ W, int wld,
    const float* __restrict__ scale_in, const float* __restrict__ shift_in,
    const float* __restrict__ bias_out,
    float* Y, int ystride,
    float* __restrict__ inv_out, const float* __restrict__ inv_mul,
    int act, int nrows) {
  constexpr int KC = 64;
  constexpr int NCHUNK = K / KC;
  constexpr int RITER = 8;
  __shared__ float sW[KC][128];
  __shared__ float sRow[4][2][KC];
  const int t = threadIdx.x;
  const int w = t >> 6;
  const int lane = t & 63;
  const int half = lane >> 5;
  const int lx = lane & 31;
  const int col0 = blockIdx.y * 128;
  const int rowBase = blockIdx.x * (8 * RITER);  // 64 rows per block
  float acc[RITER][4];
#pragma unroll
  for (int i = 0; i < RITER; ++i) {
    acc[i][0] = 0.f; acc[i][1] = 0.f; acc[i][2] = 0.f; acc[i][3] = 0.f;
  }

  for (int c = 0; c < NCHUNK; ++c) {
    const int k0 = c * KC;
    __syncthreads();
#pragma unroll
    for (int p = 0; p < 8; ++p) {
      int e4 = t + p * 256;          // 2048 float4s = KC*128 floats
      int kk = e4 >> 5;
      int ccc = (e4 & 31) << 2;
      *reinterpret_cast<float4*>(&sW[kk][ccc]) =
          *reinterpret_cast<const float4*>(W + (size_t)(k0 + kk) * wld + col0 + ccc);
    }
    __syncthreads();
    const float* Xc = (k0 < k1) ? X0 : X1;
    const int kofs = (k0 < k1) ? k0 : (k0 - k1);
#pragma unroll
    for (int it = 0; it < RITER; ++it) {
      const int r = rowBase + (w * RITER + it) * 2 + half;
      if (r < nrows) {
        float2 v = *reinterpret_cast<const float2*>(Xc + (size_t)r * xstride + kofs + 2 * lx);
        int kg = k0 + 2 * lx;
        if (scale_in) { v.x *= scale_in[kg]; v.y *= scale_in[kg + 1]; }
        if (shift_in) { v.x += shift_in[kg]; v.y += shift_in[kg + 1]; }
        sRow[w][half][2 * lx] = v.x;
        sRow[w][half][2 * lx + 1] = v.y;
      }
#pragma unroll 8
      for (int kk = 0; kk < KC; ++kk) {
        float xv = sRow[w][half][kk];
        float4 wv = *reinterpret_cast<const float4*>(&sW[kk][4 * lx]);
        acc[it][0] = fmaf(xv, wv.x, acc[it][0]);
        acc[it][1] = fmaf(xv, wv.y, acc[it][1]);
        acc[it][2] = fmaf(xv, wv.z, acc[it][2]);
        acc[it][3] = fmaf(xv, wv.w, acc[it][3]);
      }
    }
  }
  // epilogue
#pragma unroll
  for (int it = 0; it < RITER; ++it) {
    const int r = rowBase + (w * RITER + it) * 2 + half;
    float4 o = make_float4(acc[it][0], acc[it][1], acc[it][2], acc[it][3]);
    if (inv_out) {
      float ss = o.x * o.x + o.y * o.y + o.z * o.z + o.w * o.w;
#pragma unroll
      for (int m = 1; m < 32; m <<= 1) ss += __shfl_xor(ss, m, 64);
      float iv = 1.0f / fmaxf(sqrtf(ss), 1e-12f);
      if (r < nrows) {
        if (inv_mul) iv *= inv_mul[r];
        if (lx == 0) inv_out[r] = iv;
      }
    }
    if (r < nrows) {
      int cg = col0 + 4 * lx;
      if (bias_out) {
        o.x += bias_out[cg]; o.y += bias_out[cg + 1];
        o.z += bias_out[cg + 2]; o.w += bias_out[cg + 3];
      }
      if (act == 1) { o.x = gelu_f(o.x); o.y = gelu_f(o.y); o.z = gelu_f(o.z); o.w = gelu_f(o.w); }
      *reinterpret_cast<float4*>(Y + (size_t)r * ystride + cg) = o;
    }
  }
}

// ---------------- fused edge attention + aggregation ----------------
// One wave per destination node. Single pass: softmax normalization is a
// final scalar division (scores bounded: exp arg in [0, ~0.83], no max needed).
// Self-loop handled analytically. Writes agg in-place into xr (rows exclusive).
__global__ __launch_bounds__(256) void k_attn(const int* __restrict__ offs,
                                              const int* __restrict__ nbr,
                                              const float* __restrict__ xl,
                                              const float* __restrict__ ainvl,  // aux[j]*inv_l[j]
                                              float* xr,
                                              const float* __restrict__ invr, int n) {
  int node = blockIdx.x * 4 + (threadIdx.x >> 6);
  if (node >= n) return;
  int lane = threadIdx.x & 63;
  const float2 xri = *reinterpret_cast<const float2*>(xr + (size_t)node * 128 + 2 * lane);
  const float s4 = invr[node] * 4.0f;  // 1/T = 4
  // self loop (j == i)
  float2 xls = *reinterpret_cast<const float2*>(xl + (size_t)node * 128 + 2 * lane);
  float dot = wave_sum(xri.x * xls.x + xri.y * xls.y);
  float wgt = expf(fabsf(dot) * s4 * ainvl[node]);
  float denom = wgt;
  float2 acc = make_float2(wgt * xls.x, wgt * xls.y);
  int o0 = offs[node], o1 = offs[node + 1];
  for (int base = o0; base < o1; base += 64) {
    int jv = (base + lane < o1) ? nbr[base + lane] : 0;
    int cnt = min(64, o1 - base);
    for (int e = 0; e < cnt; ++e) {
      int j = __shfl(jv, e, 64);
      float2 xlj = *reinterpret_cast<const float2*>(xl + (size_t)j * 128 + 2 * lane);
      float dd = wave_sum(xri.x * xlj.x + xri.y * xlj.y);
      float wg = expf(fabsf(dd) * s4 * ainvl[j]);
      denom += wg;
      acc.x += wg * xlj.x;
      acc.y += wg * xlj.y;
    }
  }
  float rinv = 1.0f / denom;
  float2 o = make_float2(acc.x * rinv, acc.y * rinv);
  *reinterpret_cast<float2*>(xr + (size_t)node * 128 + 2 * lane) = o;
}

// ---------------- launch ----------------
extern "C" void kernel_launch(void* const* d_in, const int* in_sizes, int n_in,
                              void* d_out, int out_size, void* d_ws, size_t ws_size,
                              hipStream_t stream) {
  const float* x     = (const float*)d_in[0];
  const int*   ei    = (const int*)d_in[1];
  const float* nsa   = (const float*)d_in[2];
  const float* cin   = (const float*)d_in[3];
  const float* din   = (const float*)d_in[4];
  const float* w_in  = (const float*)d_in[5];
  const float* b_in  = (const float*)d_in[6];
  const float* bn_g  = (const float*)d_in[7];
  const float* bn_b  = (const float*)d_in[8];
  const float* lin_l = (const float*)d_in[9];
  const float* lin_r = (const float*)d_in[10];
  const float* attb  = (const float*)d_in[11];
  const float* wcat  = (const float*)d_in[12];
  const float* fw1   = (const float*)d_in[13];
  const float* fb1   = (const float*)d_in[14];
  const float* fw2   = (const float*)d_in[15];
  const float* fb2   = (const float*)d_in[16];
  const float* wproj = (const float*)d_in[17];
  const float* bproj = (const float*)d_in[18];

  const int N = in_sizes[2];       // node_score_auxiliary is [N,1]
  const int E = in_sizes[1] / 2;   // edge_index is [2,E]
  float* out = (float*)d_out;

  // workspace carve (~111 MB)
  char* p = (char*)d_ws;
  auto alloc_f = [&](size_t cnt) { float* q = (float*)p; p += ((cnt * 4 + 255) / 256) * 256; return q; };
  auto alloc_i = [&](size_t cnt) { int* q = (int*)p; p += ((cnt * 4 + 255) / 256) * 256; return q; };
  float* h     = alloc_f((size_t)N * 128);
  float* B     = alloc_f((size_t)N * 128);
  float* C     = alloc_f((size_t)N * 128);
  float* D     = alloc_f((size_t)N * 128);
  float* aux   = alloc_f(N);
  float* ainl  = alloc_f(N);
  float* invr  = alloc_f(N);
  float* stats = alloc_f(256);
  float* ab    = alloc_f(256);
  int* deg4   = alloc_i((size_t)4 * N);
  int* offs_d = alloc_i((size_t)N + 1);
  int* offs_s = alloc_i((size_t)N + 1);
  int* csr_d  = alloc_i((size_t)E);
  int* csr_s  = alloc_i((size_t)E);
  int* deg_d = deg4, * deg_s = deg4 + N, * cur_d = deg4 + 2 * (size_t)N, * cur_s = deg4 + 3 * (size_t)N;

  hipMemsetAsync(deg4, 0, (size_t)4 * N * 4, stream);

  k_aux<<<(N + 255) / 256, 256, 0, stream>>>(nsa, cin, din, aux, N);
  k_count<<<(E + 255) / 256, 256, 0, stream>>>(ei, E, deg_d, deg_s);
  k_scan<<<2, 1024, 0, stream>>>(deg_d, offs_d, deg_s, offs_s, N);
  k_scatter<<<(E + 255) / 256, 256, 0, stream>>>(ei, E, offs_d, cur_d, csr_d, offs_s, cur_s, csr_s);

  dim3 g1((N + 63) / 64, 1);
  // h = x @ w_in + b_in
  k_gemm<256><<<g1, 256, 0, stream>>>(x, x, 256, 256, w_in, 128, nullptr, nullptr,
                                      b_in, h, 128, nullptr, nullptr, 0, N);

  for (int l = 0; l < 2; ++l) {
    hipMemsetAsync(stats, 0, 256 * 4, stream);
    k_bnstats<<<512, 256, 0, stream>>>(h, stats, N * 128);
    k_bnfinal<<<1, 128, 0, stream>>>(stats, bn_g + l * 128, bn_b + l * 128, ab, 1.0f / (float)N);

    for (int d0 = 0; d0 < 2; ++d0) {
      const float* wl = lin_l + (size_t)(l * 2 + d0) * 128 * 128;
      const float* wr = lin_r + (size_t)(l * 2 + d0) * 128 * 128;
      const float* wc = wcat + (size_t)(l * 2 + d0) * 128 * 128;
      const float* abias = attb + (size_t)(l * 2 + d0) * 128;
      float* XR = (d0 == 0) ? C : D;
      // xl = bn(h) @ wl -> B, ainl[r] = aux[r]/||row||
      k_gemm<128><<<g1, 256, 0, stream>>>(h, h, 128, 128, wl, 128, ab, ab + 128,
                                          nullptr, B, 128, ainl, aux, 0, N);
      // xr = bn(h) @ wr -> XR, invr[r] = 1/||row||
      k_gemm<128><<<g1, 256, 0, stream>>>(h, h, 128, 128, wr, 128, ab, ab + 128,
                                          nullptr, XR, 128, invr, nullptr, 0, N);
      const int* offs = (d0 == 0) ? offs_d : offs_s;
      const int* csr  = (d0 == 0) ? csr_d : csr_s;
      k_attn<<<(N + 3) / 4, 256, 0, stream>>>(offs, csr, B, ainl, XR, invr, N);
      // z_half = gelu((agg + att_bias) @ wcat), in place in XR
      k_gemm<128><<<g1, 256, 0, stream>>>(XR, XR, 128, 128, wc, 128, nullptr, abias,
                                          nullptr, XR, 128, nullptr, nullptr, 1, N);
    }
    // mid = gelu([C|D] @ fw1 + fb1) -> B
    k_gemm<256><<<g1, 256, 0, stream>>>(C, D, 128, 128, fw1 + (size_t)l * 256 * 128, 128,
                                        nullptr, nullptr, fb1 + l * 128, B, 128,
                                        nullptr, nullptr, 1, N);
    // h = B @ fw2 + fb2
    k_gemm<128><<<g1, 256, 0, stream>>>(B, B, 128, 128, fw2 + (size_t)l * 128 * 128, 128,
                                        nullptr, nullptr, fb2 + l * 128, h, 128,
                                        nullptr, nullptr, 0, N);
  }
  // out = h @ w_proj + b_proj   [N,512]
  dim3 g4((N + 63) / 64, 4);
  k_gemm<128><<<g4, 256, 0, stream>>>(h, h, 128, 128, wproj, 512, nullptr, nullptr,
                                      bproj, out, 512, nullptr, nullptr, 0, N);
}

// Round 5
// 1245.885 us; speedup vs baseline: 1.6390x; 1.6390x over previous
//
#include <hip/hip_runtime.h>
#include <hip/hip_bf16.h>
#include <math.h>

typedef __attribute__((ext_vector_type(8))) short short8;
typedef __attribute__((ext_vector_type(4))) float f32x4;

// ---------------- helpers ----------------
__device__ __forceinline__ float wave_sum(float v) {
#pragma unroll
  for (int m = 1; m < 64; m <<= 1) v += __shfl_xor(v, m, 64);
  return v;
}

__device__ __forceinline__ float gelu_f(float v) {
  return 0.5f * v * (1.0f + erff(v * 0.7071067811865476f));
}

__device__ __forceinline__ unsigned short bf16rne(float f) {
  unsigned int u = __builtin_bit_cast(unsigned int, f);
  return (unsigned short)((u + 0x7fffu + ((u >> 16) & 1u)) >> 16);
}

// ---------------- tiny elementwise ----------------
__global__ void k_aux(const float* __restrict__ score, const float* __restrict__ c,
                      const float* __restrict__ d, float* __restrict__ aux, int n) {
  int i = blockIdx.x * blockDim.x + threadIdx.x;
  if (i < n) {
    float z = c[0] * score[i] - d[0];
    aux[i] = 1.0f / (1.0f + expf(-z));
  }
}

// ---------------- CSR build ----------------
__global__ void k_count(const int* __restrict__ ei, int E,
                        int* __restrict__ deg_dst, int* __restrict__ deg_src) {
  int e = blockIdx.x * blockDim.x + threadIdx.x;
  if (e < E) {
    atomicAdd(&deg_src[ei[e]], 1);
    atomicAdd(&deg_dst[ei[E + e]], 1);
  }
}

__global__ __launch_bounds__(1024) void k_scan(const int* __restrict__ degA, int* __restrict__ offA,
                                               const int* __restrict__ degB, int* __restrict__ offB,
                                               int n) {
  const int* dg = blockIdx.x ? degB : degA;
  int* of = blockIdx.x ? offB : offA;
  __shared__ int part[1024];
  int t = threadIdx.x;
  int chunk = (n + 1023) >> 10;
  int lo = t * chunk, hi = min(lo + chunk, n);
  int s = 0;
  for (int i = lo; i < hi; ++i) s += dg[i];
  part[t] = s;
  __syncthreads();
  for (int d1 = 1; d1 < 1024; d1 <<= 1) {
    int v = (t >= d1) ? part[t - d1] : 0;
    __syncthreads();
    part[t] += v;
    __syncthreads();
  }
  int run = (t == 0) ? 0 : part[t - 1];
  for (int i = lo; i < hi; ++i) { of[i] = run; run += dg[i]; }
  if (t == 1023) of[n] = part[1023];
}

__global__ void k_scatter(const int* __restrict__ ei, int E,
                          const int* __restrict__ offs_d, int* __restrict__ cur_d, int* __restrict__ csr_d,
                          const int* __restrict__ offs_s, int* __restrict__ cur_s, int* __restrict__ csr_s) {
  int e = blockIdx.x * blockDim.x + threadIdx.x;
  if (e < E) {
    int s = ei[e], dd = ei[E + e];
    int p = atomicAdd(&cur_d[dd], 1);
    csr_d[offs_d[dd] + p] = s;
    int q = atomicAdd(&cur_s[s], 1);
    csr_s[offs_s[s] + q] = dd;
  }
}

// ---------------- batchnorm stats ----------------
__global__ void k_bnstats(const float* __restrict__ h, float* __restrict__ stats, int total) {
  int t = threadIdx.x;
  int idx = blockIdx.x * 256 + t;
  int stride = gridDim.x * 256;   // multiple of 128 -> fixed column per thread
  float s = 0.f, ss = 0.f;
  for (int i = idx; i < total; i += stride) { float v = h[i]; s += v; ss += v * v; }
  __shared__ float ls[256], lss[256];
  ls[t] = s; lss[t] = ss;
  __syncthreads();
  if (t < 128) {
    s = ls[t] + ls[t + 128];
    ss = lss[t] + lss[t + 128];
    atomicAdd(&stats[t], s);
    atomicAdd(&stats[128 + t], ss);
  }
}

__global__ void k_bnfinal(const float* __restrict__ stats, const float* __restrict__ gamma,
                          const float* __restrict__ beta, float* __restrict__ ab, float invn) {
  int t = threadIdx.x;  // 128 threads
  float mu = stats[t] * invn;
  float var = stats[128 + t] * invn - mu * mu;
  float rs = rsqrtf(var + 1e-5f);
  float a = gamma[t] * rs;
  ab[t] = a;
  ab[128 + t] = beta[t] - mu * a;
}

// ---------------- weight -> MFMA-fragment pre-swizzle (bf16 hi/lo) ----------------
// B-frag layout for v_mfma_f32_16x16x32_bf16: lane l holds col = l&15,
// k = (l>>4)*8 + i (i=0..7). Stored per (ks, ct): 64 lanes x short8, hi then lo.
struct PrepEnt { const float* src; int ld, KS, NT, dst; };
struct PrepArgs { PrepEnt e[18]; };

__global__ void k_prep(PrepArgs pa, short8* __restrict__ frag) {
  PrepEnt en = pa.e[blockIdx.x];
  int tile = blockIdx.y;
  if (tile >= en.KS * en.NT) return;
  int ks = tile / en.NT;
  int ctl = tile - ks * en.NT;
  int lane = threadIdx.x;
  int col = ctl * 16 + (lane & 15);
  int k0 = ks * 32 + (lane >> 4) * 8;
  short8 hi, lo;
#pragma unroll
  for (int i = 0; i < 8; ++i) {
    float v = en.src[(size_t)(k0 + i) * en.ld + col];
    unsigned short h = bf16rne(v);
    float hf = __builtin_bit_cast(float, ((unsigned int)h) << 16);
    hi[i] = (short)h;
    lo[i] = (short)bf16rne(v - hf);
  }
  size_t base = (size_t)en.dst + (size_t)(ks * en.NT + ctl) * 128 + lane;
  frag[base] = hi;
  frag[base + 64] = lo;
}

// ---------------- MFMA GEMM (fp32 via bf16 hi/lo 3-term split) ----------------
// Y[r, (ct0+n)*16+c] = act( f(X[r,:]) @ W + bias ), f(x,k)=x*scale[k]+shift[k].
// Block: 64 rows x NT*16 cols, 4 waves (16 rows each). A loaded directly from
// global (lane: row=l&15, k=(l>>4)*8..+8 -> the wave covers 16 rows x 128B
// contiguous), converted to bf16 hi/lo in-register. W read from pre-swizzled
// frags (L2-resident). Epilogue: optional fused row-norm inv_out, bias, gelu,
// LDS transpose for float4-coalesced stores. In-place (Y==X0) is safe: rows
// are block-exclusive and all A reads precede the store phase.
template<int KS, int NT>
__global__ __launch_bounds__(256) void k_mf(
    const float* __restrict__ X0, const float* __restrict__ X1, int k1, int xstride,
    const short8* __restrict__ Wf, int NTtot,
    const float* __restrict__ scale_in, const float* __restrict__ shift_in,
    const float* __restrict__ bias_out,
    float* __restrict__ Y, int ystride,
    float* __restrict__ inv0, const float* __restrict__ mul0,
    int act, int nrows) {
  __shared__ float sY[64][NT * 16];
  const int tid = threadIdx.x;
  const int w = tid >> 6;
  const int l = tid & 63;
  const int lhi = l >> 4, llo = l & 15;
  const int ct0 = blockIdx.y * NT;
  const int blockRow = blockIdx.x * 64;
  const int rowA = blockRow + w * 16 + llo;
  const int rA = min(rowA, nrows - 1);
  f32x4 acc[NT];
#pragma unroll
  for (int n = 0; n < NT; ++n) { f32x4 z = {0.f, 0.f, 0.f, 0.f}; acc[n] = z; }

  for (int ks = 0; ks < KS; ++ks) {
    const int kg = ks * 32 + lhi * 8;
    const float* Xc = X0;
    int ko = kg;
    if (kg >= k1) { Xc = X1; ko = kg - k1; }
    const float* ap = Xc + (size_t)rA * xstride + ko;
    float4 a0 = *(const float4*)ap;
    float4 a1 = *(const float4*)(ap + 4);
    if (scale_in) {
      float4 s0 = *(const float4*)(scale_in + kg);
      float4 s1 = *(const float4*)(scale_in + kg + 4);
      a0.x *= s0.x; a0.y *= s0.y; a0.z *= s0.z; a0.w *= s0.w;
      a1.x *= s1.x; a1.y *= s1.y; a1.z *= s1.z; a1.w *= s1.w;
    }
    if (shift_in) {
      float4 s0 = *(const float4*)(shift_in + kg);
      float4 s1 = *(const float4*)(shift_in + kg + 4);
      a0.x += s0.x; a0.y += s0.y; a0.z += s0.z; a0.w += s0.w;
      a1.x += s1.x; a1.y += s1.y; a1.z += s1.z; a1.w += s1.w;
    }
    float av[8] = {a0.x, a0.y, a0.z, a0.w, a1.x, a1.y, a1.z, a1.w};
    short8 ahi, alo;
#pragma unroll
    for (int i = 0; i < 8; ++i) {
      unsigned short hh = bf16rne(av[i]);
      float hf = __builtin_bit_cast(float, ((unsigned int)hh) << 16);
      ahi[i] = (short)hh;
      alo[i] = (short)bf16rne(av[i] - hf);
    }
    const short8* wp = Wf + ((size_t)(ks * NTtot + ct0) * 128) + l;
#pragma unroll
    for (int n = 0; n < NT; ++n) {
      short8 bhi = wp[n * 128];
      short8 blo = wp[n * 128 + 64];
      acc[n] = __builtin_amdgcn_mfma_f32_16x16x32_bf16(alo, bhi, acc[n], 0, 0, 0);
      acc[n] = __builtin_amdgcn_mfma_f32_16x16x32_bf16(ahi, blo, acc[n], 0, 0, 0);
      acc[n] = __builtin_amdgcn_mfma_f32_16x16x32_bf16(ahi, bhi, acc[n], 0, 0, 0);
    }
  }

  // C/D layout: col = l&15, row(in 16-tile) = (l>>4)*4 + j  [verified m89]
  if (inv0) {
    float ss[4] = {0.f, 0.f, 0.f, 0.f};
#pragma unroll
    for (int n = 0; n < NT; ++n) {
#pragma unroll
      for (int j = 0; j < 4; ++j) ss[j] += acc[n][j] * acc[n][j];
    }
#pragma unroll
    for (int j = 0; j < 4; ++j) {
      ss[j] += __shfl_xor(ss[j], 1, 64);
      ss[j] += __shfl_xor(ss[j], 2, 64);
      ss[j] += __shfl_xor(ss[j], 4, 64);
      ss[j] += __shfl_xor(ss[j], 8, 64);
    }
    if (llo == 0) {
#pragma unroll
      for (int j = 0; j < 4; ++j) {
        int rj = blockRow + w * 16 + lhi * 4 + j;
        if (rj < nrows) {
          float iv = 1.0f / fmaxf(sqrtf(ss[j]), 1e-12f);
          if (mul0) iv *= mul0[rj];
          inv0[rj] = iv;
        }
      }
    }
  }
#pragma unroll
  for (int n = 0; n < NT; ++n) {
    int cloc = n * 16 + llo;
    float b = bias_out ? bias_out[ct0 * 16 + cloc] : 0.f;
#pragma unroll
    for (int j = 0; j < 4; ++j) {
      float v = acc[n][j] + b;
      if (act) v = gelu_f(v);
      sY[w * 16 + lhi * 4 + j][cloc] = v;
    }
  }
  __syncthreads();
  const int C4 = NT * 4;  // float4s per row
  for (int idx = tid; idx < 64 * C4; idx += 256) {
    int row = idx / C4;
    int c4 = (idx - row * C4) * 4;
    int gr = blockRow + row;
    if (gr < nrows)
      *(float4*)(Y + (size_t)gr * ystride + ct0 * 16 + c4) = *(const float4*)&sY[row][c4];
  }
}

// ---------------- fused edge attention + aggregation ----------------
// One wave per destination node; single pass (exp arg bounded in [0,~0.83],
// no max subtraction needed); self-loop analytic; agg written in-place to xr.
__global__ __launch_bounds__(256) void k_attn(const int* __restrict__ offs,
                                              const int* __restrict__ nbr,
                                              const float* __restrict__ xl,
                                              const float* __restrict__ ainvl,  // aux[j]*inv_l[j]
                                              float* xr,
                                              const float* __restrict__ invr, int n) {
  int node = blockIdx.x * 4 + (threadIdx.x >> 6);
  if (node >= n) return;
  int lane = threadIdx.x & 63;
  const float2 xri = *reinterpret_cast<const float2*>(xr + (size_t)node * 128 + 2 * lane);
  const float s4 = invr[node] * 4.0f;  // 1/T = 4
  float2 xls = *reinterpret_cast<const float2*>(xl + (size_t)node * 128 + 2 * lane);
  float dot = wave_sum(xri.x * xls.x + xri.y * xls.y);
  float wgt = expf(fabsf(dot) * s4 * ainvl[node]);
  float denom = wgt;
  float2 acc = make_float2(wgt * xls.x, wgt * xls.y);
  int o0 = offs[node], o1 = offs[node + 1];
  for (int base = o0; base < o1; base += 64) {
    int jv = (base + lane < o1) ? nbr[base + lane] : 0;
    int cnt = min(64, o1 - base);
    for (int e = 0; e < cnt; ++e) {
      int j = __shfl(jv, e, 64);
      float2 xlj = *reinterpret_cast<const float2*>(xl + (size_t)j * 128 + 2 * lane);
      float dd = wave_sum(xri.x * xlj.x + xri.y * xlj.y);
      float wg = expf(fabsf(dd) * s4 * ainvl[j]);
      denom += wg;
      acc.x += wg * xlj.x;
      acc.y += wg * xlj.y;
    }
  }
  float rinv = 1.0f / denom;
  float2 o = make_float2(acc.x * rinv, acc.y * rinv);
  *reinterpret_cast<float2*>(xr + (size_t)node * 128 + 2 * lane) = o;
}

// ---------------- launch ----------------
extern "C" void kernel_launch(void* const* d_in, const int* in_sizes, int n_in,
                              void* d_out, int out_size, void* d_ws, size_t ws_size,
                              hipStream_t stream) {
  const float* x     = (const float*)d_in[0];
  const int*   ei    = (const int*)d_in[1];
  const float* nsa   = (const float*)d_in[2];
  const float* cin   = (const float*)d_in[3];
  const float* din   = (const float*)d_in[4];
  const float* w_in  = (const float*)d_in[5];
  const float* b_in  = (const float*)d_in[6];
  const float* bn_g  = (const float*)d_in[7];
  const float* bn_b  = (const float*)d_in[8];
  const float* lin_l = (const float*)d_in[9];
  const float* lin_r = (const float*)d_in[10];
  const float* attb  = (const float*)d_in[11];
  const float* wcat  = (const float*)d_in[12];
  const float* fw1   = (const float*)d_in[13];
  const float* fb1   = (const float*)d_in[14];
  const float* fw2   = (const float*)d_in[15];
  const float* fb2   = (const float*)d_in[16];
  const float* wproj = (const float*)d_in[17];
  const float* bproj = (const float*)d_in[18];

  const int N = in_sizes[2];
  const int E = in_sizes[1] / 2;
  float* out = (float*)d_out;

  // workspace carve (~62 MB; C and D live in d_out's first 2*N*128 floats —
  // d_out [N,512] is dead until the final projection, and C/D are fully
  // consumed by FFN1 before that).
  char* p = (char*)d_ws;
  auto alloc_f = [&](size_t cnt) { float* q = (float*)p; p += ((cnt * 4 + 255) / 256) * 256; return q; };
  auto alloc_i = [&](size_t cnt) { int* q = (int*)p; p += ((cnt * 4 + 255) / 256) * 256; return q; };
  float* h     = alloc_f((size_t)N * 128);
  float* B     = alloc_f((size_t)N * 128);
  float* C     = out;
  float* D     = out + (size_t)N * 128;
  float* aux   = alloc_f(N);
  float* ainl  = alloc_f(N);
  float* invr  = alloc_f(N);
  float* stats = alloc_f(256);
  float* ab    = alloc_f(256);
  // frag pool: descriptors below total 98304 short8s (1.57 MB); reserve 2 MB.
  short8* frag = (short8*)p; p += (size_t)131072 * 16;
  int* deg4   = alloc_i((size_t)4 * N);
  int* offs_d = alloc_i((size_t)N + 1);
  int* offs_s = alloc_i((size_t)N + 1);
  int* csr_d  = alloc_i((size_t)E);
  int* csr_s  = alloc_i((size_t)E);
  int* deg_d = deg4, * deg_s = deg4 + N, * cur_d = deg4 + 2 * (size_t)N, * cur_s = deg4 + 3 * (size_t)N;

  // ---- weight frag prep descriptors ----
  PrepArgs pa;
  int off16 = 0, ne = 0;
  auto add = [&](const float* src, int ld, int KS, int NT) {
    pa.e[ne].src = src; pa.e[ne].ld = ld; pa.e[ne].KS = KS; pa.e[ne].NT = NT;
    pa.e[ne].dst = off16; ne++;
    int sz = KS * NT * 128; off16 += sz; return off16 - sz;
  };
  int f_win = add(w_in, 128, 8, 8);
  int f_wl[2][2], f_wr[2][2], f_wc[2][2], f_f1[2], f_f2[2];
  for (int l = 0; l < 2; ++l)
    for (int d0 = 0; d0 < 2; ++d0)
      f_wl[l][d0] = add(lin_l + (size_t)(l * 2 + d0) * 16384, 128, 4, 8);
  for (int l = 0; l < 2; ++l)
    for (int d0 = 0; d0 < 2; ++d0)
      f_wr[l][d0] = add(lin_r + (size_t)(l * 2 + d0) * 16384, 128, 4, 8);
  for (int l = 0; l < 2; ++l)
    for (int d0 = 0; d0 < 2; ++d0)
      f_wc[l][d0] = add(wcat + (size_t)(l * 2 + d0) * 16384, 128, 4, 8);
  for (int l = 0; l < 2; ++l) f_f1[l] = add(fw1 + (size_t)l * 32768, 128, 8, 8);
  for (int l = 0; l < 2; ++l) f_f2[l] = add(fw2 + (size_t)l * 16384, 128, 4, 8);
  int f_wp = add(wproj, 512, 4, 32);
  // ne == 18, off16 == 98304 (fits the 131072 reservation)

  hipMemsetAsync(deg4, 0, (size_t)4 * N * 4, stream);
  k_prep<<<dim3(18, 128), 64, 0, stream>>>(pa, frag);
  k_aux<<<(N + 255) / 256, 256, 0, stream>>>(nsa, cin, din, aux, N);
  k_count<<<(E + 255) / 256, 256, 0, stream>>>(ei, E, deg_d, deg_s);
  k_scan<<<2, 1024, 0, stream>>>(deg_d, offs_d, deg_s, offs_s, N);
  k_scatter<<<(E + 255) / 256, 256, 0, stream>>>(ei, E, offs_d, cur_d, csr_d, offs_s, cur_s, csr_s);

  const int blocksM = (N + 63) / 64;
  dim3 g1(blocksM, 1);
  // h = x @ w_in + b_in
  k_mf<8, 8><<<g1, 256, 0, stream>>>(x, x, 256, 256, frag + f_win, 8,
                                     nullptr, nullptr, b_in, h, 128,
                                     nullptr, nullptr, 0, N);

  for (int l = 0; l < 2; ++l) {
    hipMemsetAsync(stats, 0, 256 * 4, stream);
    k_bnstats<<<512, 256, 0, stream>>>(h, stats, N * 128);
    k_bnfinal<<<1, 128, 0, stream>>>(stats, bn_g + l * 128, bn_b + l * 128, ab, 1.0f / (float)N);

    for (int d0 = 0; d0 < 2; ++d0) {
      const float* abias = attb + (size_t)(l * 2 + d0) * 128;
      float* XR = (d0 == 0) ? C : D;
      // xl = bn(h) @ wl -> B, ainl[r] = aux[r]/||row||
      k_mf<4, 8><<<g1, 256, 0, stream>>>(h, h, 128, 128, frag + f_wl[l][d0], 8,
                                         ab, ab + 128, nullptr, B, 128,
                                         ainl, aux, 0, N);
      // xr = bn(h) @ wr -> XR, invr[r] = 1/||row||
      k_mf<4, 8><<<g1, 256, 0, stream>>>(h, h, 128, 128, frag + f_wr[l][d0], 8,
                                         ab, ab + 128, nullptr, XR, 128,
                                         invr, nullptr, 0, N);
      const int* offs = (d0 == 0) ? offs_d : offs_s;
      const int* csr  = (d0 == 0) ? csr_d : csr_s;
      k_attn<<<(N + 3) / 4, 256, 0, stream>>>(offs, csr, B, ainl, XR, invr, N);
      // z_half = gelu((agg + att_bias) @ wcat), in place in XR
      k_mf<4, 8><<<g1, 256, 0, stream>>>(XR, XR, 128, 128, frag + f_wc[l][d0], 8,
                                         nullptr, abias, nullptr, XR, 128,
                                         nullptr, nullptr, 1, N);
    }
    // mid = gelu([C|D] @ fw1 + fb1) -> B
    k_mf<8, 8><<<g1, 256, 0, stream>>>(C, D, 128, 128, frag + f_f1[l], 8,
                                       nullptr, nullptr, fb1 + l * 128, B, 128,
                                       nullptr, nullptr, 1, N);
    // h = B @ fw2 + fb2
    k_mf<4, 8><<<g1, 256, 0, stream>>>(B, B, 128, 128, frag + f_f2[l], 8,
                                       nullptr, nullptr, fb2 + l * 128, h, 128,
                                       nullptr, nullptr, 0, N);
  }
  // out = h @ w_proj + b_proj   [N,512]  (4 column tiles of 128; NTtot=32)
  dim3 g2(blocksM, 4);
  k_mf<4, 8><<<g2, 256, 0, stream>>>(h, h, 128, 128, frag + f_wp, 32,
                                     nullptr, nullptr, bproj, out, 512,
                                     nullptr, nullptr, 0, N);
}